// Round 2
// baseline (253.179 us; speedup 1.0000x reference)
//
#include <hip/hip_runtime.h>

// Problem constants
#define BATCH 2
#define LSEQ 384
#define NHID 512
#define NH 8
#define DH 64
#define BH (BATCH*NH)          // 16
#define MROWS (BATCH*LSEQ)     // 768
#define XELEMS ((size_t)MROWS * NHID)      // 393216 (x output elems)

typedef unsigned short ushort_t;

__device__ __forceinline__ float bf2f(ushort_t u) {
    unsigned int v = ((unsigned int)u) << 16;
    return __uint_as_float(v);
}
__device__ __forceinline__ ushort_t f2bf(float f) {
    unsigned int u = __float_as_uint(f);
    unsigned int lsb = (u >> 16) & 1u;
    u += 0x7fffu + lsb;           // round-to-nearest-even
    return (ushort_t)(u >> 16);
}
__device__ __forceinline__ float fast_tanh(float x) {
    float e = __expf(2.0f * x);
    return 1.0f - 2.0f * __builtin_amdgcn_rcpf(e + 1.0f);
}

// ---------------- workspace layout (float offsets) ----------------
#define OFF_FLAG  0          // int flag in ws[0]
#define OFF_QF    16
#define OFF_KF    393232
#define OFF_VF    786448
#define OFF_WQ    1179664
#define OFF_WK    1441808
#define OFF_WV    1703952
#define OFF_WO    1966096
#define OFF_BQ    2228240
#define OFF_BK    2228752
#define OFF_BV    2229264
#define OFF_BO    2229776
#define OFF_W1    2230288
#define OFF_W2    2234384
#define OFF_B1    2238480
#define OFF_B2    2238544
#define OFF_VW    2238608
#define OFF_VB    2238672
#define OFF_WQE   2238688
#define OFF_WKE   2500832
#define OFF_BQE   2762976
#define OFF_BKE   2763488
#define OFF_TQ    2764000
#define OFF_TKT   3157216
#define OFF_VH    3550432
#define OFF_XH    3943648
// end = 4336864 floats = 17.35 MB

// ---------------------------------------------------------------------------
// Kernel 0: detect whether float inputs are packed-bf16 (flag=0) or fp32 (flag=1)
// ---------------------------------------------------------------------------
__global__ __launch_bounds__(256) void detect_dtype(const unsigned int* __restrict__ q,
                                                    int* __restrict__ flag)
{
    __shared__ int cnt;
    int t = threadIdx.x;
    if (t == 0) cnt = 0;
    __syncthreads();
    unsigned int w = q[t];
    unsigned int elo = (w >> 7) & 0xFFu;   // low halfword's bf16 exponent field
    int isbf = (elo >= 100u && elo <= 150u) ? 1 : 0;
    atomicAdd(&cnt, isbf);
    __syncthreads();
    if (t == 0) *flag = (cnt > 128) ? 0 : 1;   // 0 = bf16-packed, 1 = fp32
}

// ---------------------------------------------------------------------------
// Kernel 1: convert all 17 float inputs into fp32 canonical ws buffers.
// ---------------------------------------------------------------------------
struct Srcs { const void* p[17]; };

__device__ const int g_segsz[17] = {
    393216, 393216, 393216, 262144, 512, 262144, 512, 262144, 512,
    262144, 512, 4096, 64, 4096, 64, 64, 1
};
__device__ const int g_dof[17] = {
    OFF_QF, OFF_KF, OFF_VF, OFF_WQ, OFF_BQ, OFF_WK, OFF_BK, OFF_WV, OFF_BV,
    OFF_WO, OFF_BO, OFF_W1, OFF_B1, OFF_W2, OFF_B2, OFF_VW, OFF_VB
};
#define CONV_TOTAL 2238657

__global__ __launch_bounds__(256) void convert_inputs(Srcs s, float* __restrict__ ws,
                                                      const int* __restrict__ flag)
{
    int f = *flag;
    for (int gid = blockIdx.x * 256 + threadIdx.x; gid < CONV_TOTAL;
         gid += gridDim.x * 256) {
        int r = gid, seg = 0;
        while (r >= g_segsz[seg]) { r -= g_segsz[seg]; seg++; }
        float v = f ? ((const float*)s.p[seg])[r]
                    : bf2f(((const ushort_t*)s.p[seg])[r]);
        ws[g_dof[seg] + r] = v;
    }
}

// ---------------------------------------------------------------------------
// Kernel 2: fold W1 into Wq, W2 into Wk (per-head), plus fused biases.
// ---------------------------------------------------------------------------
__global__ __launch_bounds__(256) void fuse_weights(const float* __restrict__ ws_in,
                                                    float* __restrict__ ws)
{
    const float* Wq = ws_in + OFF_WQ;
    const float* Wk = ws_in + OFF_WK;
    const float* W1 = ws_in + OFF_W1;
    const float* W2 = ws_in + OFF_W2;
    const float* bq = ws_in + OFF_BQ;
    const float* bk = ws_in + OFF_BK;
    const float* b1 = ws_in + OFF_B1;
    const float* b2 = ws_in + OFF_B2;
    float* WqE = ws + OFF_WQE;
    float* WkE = ws + OFF_WKE;
    float* bqE = ws + OFF_BQE;
    float* bkE = ws + OFF_BKE;

    int gid = blockIdx.x * 256 + threadIdx.x;   // 0 .. 512*512-1
    int o = gid >> 9;          // output feature (h*64+od)
    int i = gid & 511;         // input feature
    int h = o >> 6, od = o & 63;
    float aq = 0.f, ak = 0.f;
    for (int j = 0; j < 64; j++) {
        aq = fmaf(W1[od * 64 + j], Wq[(h * 64 + j) * 512 + i], aq);
        ak = fmaf(W2[od * 64 + j], Wk[(h * 64 + j) * 512 + i], ak);
    }
    WqE[o * 512 + i] = aq;
    WkE[o * 512 + i] = ak;
    if (i == 0) {
        float sq = b1[od], sk = b2[od];
        for (int j = 0; j < 64; j++) {
            sq = fmaf(W1[od * 64 + j], bq[h * 64 + j], sq);
            sk = fmaf(W2[od * 64 + j], bk[h * 64 + j], sk);
        }
        bqE[o] = sq; bkE[o] = sk;
    }
}

// ---------------------------------------------------------------------------
// Kernel 3: QKV projection GEMM. C[768,512] = A[768,512] @ W.T + b (all fp32).
// z=0 -> tQ [bh][l][d], z=1 -> tK transposed [bh][d][l], z=2 -> V [bh][l][d]
// ---------------------------------------------------------------------------
__global__ __launch_bounds__(256) void gemm_qkv(const float* __restrict__ ws_in,
                                                float* __restrict__ ws)
{
    const int mode = blockIdx.z;
    const float* A    = ws_in + ((mode == 0) ? OFF_QF  : (mode == 1) ? OFF_KF  : OFF_VF);
    const float* W    = ws_in + ((mode == 0) ? OFF_WQE : (mode == 1) ? OFF_WKE : OFF_WV);
    const float* bias = ws_in + ((mode == 0) ? OFF_BQE : (mode == 1) ? OFF_BKE : OFF_BV);
    float* Out        = ws    + ((mode == 0) ? OFF_TQ  : (mode == 1) ? OFF_TKT : OFF_VH);

    __shared__ float As[64][17];
    __shared__ float Bs[16][64];

    const int tid = threadIdx.x;
    const int row0 = blockIdx.y * 64;
    const int col0 = blockIdx.x * 64;
    const int ty = tid >> 4, tx = tid & 15;
    const int lm = tid >> 2;
    const int lk = (tid & 3) << 2;

    float acc[4][4];
    #pragma unroll
    for (int i = 0; i < 4; i++)
        #pragma unroll
        for (int j = 0; j < 4; j++) acc[i][j] = 0.f;

    for (int k0 = 0; k0 < 512; k0 += 16) {
        float4 av = *reinterpret_cast<const float4*>(A + (row0 + lm) * 512 + k0 + lk);
        float4 wv = *reinterpret_cast<const float4*>(W + (col0 + lm) * 512 + k0 + lk);
        __syncthreads();
        As[lm][lk + 0] = av.x; As[lm][lk + 1] = av.y;
        As[lm][lk + 2] = av.z; As[lm][lk + 3] = av.w;
        Bs[lk + 0][lm] = wv.x; Bs[lk + 1][lm] = wv.y;
        Bs[lk + 2][lm] = wv.z; Bs[lk + 3][lm] = wv.w;
        __syncthreads();
        #pragma unroll
        for (int kk = 0; kk < 16; kk++) {
            float a0 = As[ty * 4 + 0][kk], a1 = As[ty * 4 + 1][kk];
            float a2 = As[ty * 4 + 2][kk], a3 = As[ty * 4 + 3][kk];
            float b0 = Bs[kk][tx * 4 + 0], b1 = Bs[kk][tx * 4 + 1];
            float b2 = Bs[kk][tx * 4 + 2], b3 = Bs[kk][tx * 4 + 3];
            acc[0][0] = fmaf(a0, b0, acc[0][0]); acc[0][1] = fmaf(a0, b1, acc[0][1]);
            acc[0][2] = fmaf(a0, b2, acc[0][2]); acc[0][3] = fmaf(a0, b3, acc[0][3]);
            acc[1][0] = fmaf(a1, b0, acc[1][0]); acc[1][1] = fmaf(a1, b1, acc[1][1]);
            acc[1][2] = fmaf(a1, b2, acc[1][2]); acc[1][3] = fmaf(a1, b3, acc[1][3]);
            acc[2][0] = fmaf(a2, b0, acc[2][0]); acc[2][1] = fmaf(a2, b1, acc[2][1]);
            acc[2][2] = fmaf(a2, b2, acc[2][2]); acc[2][3] = fmaf(a2, b3, acc[2][3]);
            acc[3][0] = fmaf(a3, b0, acc[3][0]); acc[3][1] = fmaf(a3, b1, acc[3][1]);
            acc[3][2] = fmaf(a3, b2, acc[3][2]); acc[3][3] = fmaf(a3, b3, acc[3][3]);
        }
    }

    #pragma unroll
    for (int i = 0; i < 4; i++) {
        int m = row0 + ty * 4 + i;
        int bb = m / LSEQ, ll = m % LSEQ;
        #pragma unroll
        for (int j = 0; j < 4; j++) {
            int n = col0 + tx * 4 + j;
            float c = acc[i][j] + bias[n];
            int hh = n >> 6, dd = n & 63;
            int bh = bb * NH + hh;
            size_t off = (mode == 1) ? ((size_t)(bh * 64 + dd) * LSEQ + ll)
                                     : ((size_t)(bh * LSEQ + ll) * 64 + dd);
            Out[off] = c;
        }
    }
}

// ---------------------------------------------------------------------------
// Kernel 4: additive attention. One block per (b,h,q); 384 threads = 1 per k.
// ---------------------------------------------------------------------------
__global__ __launch_bounds__(384) void attn_kernel(const float* __restrict__ ws_in,
                                                   float* __restrict__ ws,
                                                   const int* __restrict__ mask,
                                                   void* __restrict__ dout,
                                                   const int* __restrict__ flag)
{
    const float* tQ  = ws_in + OFF_TQ;
    const float* tKt = ws_in + OFF_TKT;
    const float* Vh  = ws_in + OFF_VH;
    const float* vwf = ws_in + OFF_VW;
    const float* vbf = ws_in + OFF_VB;
    float* Xh = ws + OFF_XH;

    const int bid = blockIdx.x;            // (b*NH + h)*LSEQ + q
    const int q  = bid % LSEQ;
    const int bh = bid / LSEQ;
    const int b  = bh >> 3;
    const int h  = bh & 7;
    const int t  = threadIdx.x;            // 0..383 (= k)
    const int f  = *flag;

    __shared__ float tq[64];
    __shared__ float vw[64];
    __shared__ float ps[LSEQ];
    __shared__ float red[6][64];
    __shared__ float rmax[6];
    __shared__ float rsum[6];

    if (t < 64) {
        tq[t] = tQ[(size_t)(bh * LSEQ + q) * 64 + t];
        vw[t] = vwf[t];
    }
    __syncthreads();

    const float* tkbase = tKt + (size_t)bh * 64 * LSEQ;   // [d][k]
    float e = vbf[0];
    #pragma unroll 16
    for (int d = 0; d < 64; d++) {
        float x = tq[d] + tkbase[d * LSEQ + t];
        e = fmaf(vw[d], fast_tanh(x), e);
    }
    if (mask[b * LSEQ + t] == 0) e = -1e10f;

    const int wave = t >> 6;
    float m = e;
    #pragma unroll
    for (int off = 32; off > 0; off >>= 1) m = fmaxf(m, __shfl_xor(m, off, 64));
    if ((t & 63) == 0) rmax[wave] = m;
    __syncthreads();
    float gm = fmaxf(fmaxf(fmaxf(rmax[0], rmax[1]), fmaxf(rmax[2], rmax[3])),
                     fmaxf(rmax[4], rmax[5]));
    float p = __expf(e - gm);
    float s = p;
    #pragma unroll
    for (int off = 32; off > 0; off >>= 1) s += __shfl_xor(s, off, 64);
    if ((t & 63) == 0) rsum[wave] = s;
    __syncthreads();
    float gs = rsum[0] + rsum[1] + rsum[2] + rsum[3] + rsum[4] + rsum[5];
    p *= 1.0f / gs;

    ps[t] = p;
    size_t aidx = XELEMS + (size_t)bid * LSEQ + t;   // attention output region
    if (f) ((float*)dout)[aidx] = p;
    else   ((ushort_t*)dout)[aidx] = f2bf(p);
    __syncthreads();

    // context: x[d] = sum_k p[k] * V[k][d]
    const int g = wave;
    const int d = t & 63;
    const float* vbase = Vh + (size_t)bh * LSEQ * 64;
    float acc = 0.f;
    #pragma unroll 8
    for (int kk = g * 64; kk < g * 64 + 64; kk++)
        acc = fmaf(ps[kk], vbase[kk * 64 + d], acc);
    red[g][d] = acc;
    __syncthreads();
    if (t < 64) {
        float sx = red[0][t] + red[1][t] + red[2][t] +
                   red[3][t] + red[4][t] + red[5][t];
        Xh[((size_t)(b * LSEQ + q) * NH + h) * 64 + t] = sx;   // [B,L,H,D]
    }
}

// ---------------------------------------------------------------------------
// Kernel 5: output projection. x[768,512] = Xh @ Wo.T + bo.
// ---------------------------------------------------------------------------
__global__ __launch_bounds__(256) void gemm_out(const float* __restrict__ ws_in,
                                                void* __restrict__ dout,
                                                const int* __restrict__ flag)
{
    const float* Xh = ws_in + OFF_XH;
    const float* Wo = ws_in + OFF_WO;
    const float* bo = ws_in + OFF_BO;

    __shared__ float As[64][17];
    __shared__ float Bs[16][64];

    const int tid = threadIdx.x;
    const int row0 = blockIdx.y * 64;
    const int col0 = blockIdx.x * 64;
    const int ty = tid >> 4, tx = tid & 15;
    const int lm = tid >> 2;
    const int lk = (tid & 3) << 2;
    const int f = *flag;

    float acc[4][4];
    #pragma unroll
    for (int i = 0; i < 4; i++)
        #pragma unroll
        for (int j = 0; j < 4; j++) acc[i][j] = 0.f;

    for (int k0 = 0; k0 < 512; k0 += 16) {
        float4 av = *reinterpret_cast<const float4*>(Xh + (row0 + lm) * 512 + k0 + lk);
        float4 wv = *reinterpret_cast<const float4*>(Wo + (col0 + lm) * 512 + k0 + lk);
        __syncthreads();
        As[lm][lk + 0] = av.x; As[lm][lk + 1] = av.y;
        As[lm][lk + 2] = av.z; As[lm][lk + 3] = av.w;
        Bs[lk + 0][lm] = wv.x; Bs[lk + 1][lm] = wv.y;
        Bs[lk + 2][lm] = wv.z; Bs[lk + 3][lm] = wv.w;
        __syncthreads();
        #pragma unroll
        for (int kk = 0; kk < 16; kk++) {
            float a0 = As[ty * 4 + 0][kk], a1 = As[ty * 4 + 1][kk];
            float a2 = As[ty * 4 + 2][kk], a3 = As[ty * 4 + 3][kk];
            float b0 = Bs[kk][tx * 4 + 0], b1 = Bs[kk][tx * 4 + 1];
            float b2 = Bs[kk][tx * 4 + 2], b3 = Bs[kk][tx * 4 + 3];
            acc[0][0] = fmaf(a0, b0, acc[0][0]); acc[0][1] = fmaf(a0, b1, acc[0][1]);
            acc[0][2] = fmaf(a0, b2, acc[0][2]); acc[0][3] = fmaf(a0, b3, acc[0][3]);
            acc[1][0] = fmaf(a1, b0, acc[1][0]); acc[1][1] = fmaf(a1, b1, acc[1][1]);
            acc[1][2] = fmaf(a1, b2, acc[1][2]); acc[1][3] = fmaf(a1, b3, acc[1][3]);
            acc[2][0] = fmaf(a2, b0, acc[2][0]); acc[2][1] = fmaf(a2, b1, acc[2][1]);
            acc[2][2] = fmaf(a2, b2, acc[2][2]); acc[2][3] = fmaf(a2, b3, acc[2][3]);
            acc[3][0] = fmaf(a3, b0, acc[3][0]); acc[3][1] = fmaf(a3, b1, acc[3][1]);
            acc[3][2] = fmaf(a3, b2, acc[3][2]); acc[3][3] = fmaf(a3, b3, acc[3][3]);
        }
    }

    #pragma unroll
    for (int i = 0; i < 4; i++) {
        int m = row0 + ty * 4 + i;
        #pragma unroll
        for (int j = 0; j < 4; j++) {
            int n = col0 + tx * 4 + j;
            float c = acc[i][j] + bo[n];
            size_t idx = (size_t)m * 512 + n;
            if (f) ((float*)dout)[idx] = c;
            else   ((ushort_t*)dout)[idx] = f2bf(c);
        }
    }
}

// ---------------------------------------------------------------------------
extern "C" void kernel_launch(void* const* d_in, const int* in_sizes, int n_in,
                              void* d_out, int out_size, void* d_ws, size_t ws_size,
                              hipStream_t stream)
{
    const int* mask = (const int*)d_in[3];
    float* ws = (float*)d_ws;
    int* flag = (int*)d_ws;       // ws[0]

    Srcs s;
    // float inputs in order, skipping mask (d_in[3])
    const int map[17] = {0,1,2,4,5,6,7,8,9,10,11,12,13,14,15,16,17};
    for (int i = 0; i < 17; i++) s.p[i] = d_in[map[i]];

    detect_dtype<<<1, 256, 0, stream>>>((const unsigned int*)d_in[0], flag);
    convert_inputs<<<2048, 256, 0, stream>>>(s, ws, flag);
    fuse_weights<<<1024, 256, 0, stream>>>(ws, ws);
    gemm_qkv<<<dim3(8, 12, 3), 256, 0, stream>>>(ws, ws);
    attn_kernel<<<BH * LSEQ, 384, 0, stream>>>(ws, ws, mask, d_out, flag);
    gemm_out<<<dim3(8, 12, 1), 256, 0, stream>>>(ws, d_out, flag);
}